// Round 4
// baseline (1006.866 us; speedup 1.0000x reference)
//
#include <hip/hip_runtime.h>

typedef float v16f __attribute__((ext_vector_type(16)));
typedef _Float16 v8h __attribute__((ext_vector_type(8)));

#define NROWS 131072
#define DIM 128
#define NCB 4
#define CBS 2048
#define ZQ_SIZE ((size_t)NROWS * DIM)
#define CODES_SIZE ((size_t)NROWS * NCB)
#define CHUNK_BYTES 16384
#define CBQ_TOTAL ((size_t)NCB * 64 * CHUNK_BYTES)  /* 4 MiB */
#define INV4096 2.44140625e-4f

#define MFMA16(a, b, c) __builtin_amdgcn_mfma_f32_32x32x16_f16((a), (b), (c), 0, 0, 0)

// Tile codebook into per-chunk f16 2-limb image (identical to round 3).
__global__ void prep_cb(const float* __restrict__ cb, _Float16* __restrict__ cbq) {
    const int g = blockIdx.x * 256 + threadIdx.x;   // 65536 threads
    const int c   = g & 7;
    const int col = (g >> 3) & 31;
    const int q   = (g >> 8) & 63;
    const int s   = g >> 14;
    const float* src = cb + (size_t)(s * CBS + q * 32 + col) * DIM + 16 * c;
    _Float16* base = cbq + (size_t)(s * 64 + q) * 8192;  // f16 elems
#pragma unroll
    for (int hh = 0; hh < 2; ++hh) {
        v8h p0, p1;
#pragma unroll
        for (int j = 0; j < 8; ++j) {
            const float v = src[8 * hh + j];
            const _Float16 h0 = (_Float16)v;
            const float t = v - (float)h0;        // exact
            p0[j] = h0;
            p1[j] = (_Float16)(t * 4096.0f);      // scaled limb: normal range
        }
        *reinterpret_cast<v8h*>(base + (size_t)c * 512 + (hh * 32 + col) * 8) = p0;
        *reinterpret_cast<v8h*>(base + (size_t)(8 + c) * 512 + (hh * 32 + col) * 8) = p1;
    }
}

__global__ void prep_cn(const float* __restrict__ cb, float* __restrict__ cn) {
    const int g = blockIdx.x * 256 + threadIdx.x;   // 8192 threads
    const float* src = cb + (size_t)g * DIM;
    float acc = 0.0f;
    for (int i = 0; i < 32; ++i) {
        const float4 v = *reinterpret_cast<const float4*>(src + 4 * i);
        acc = fmaf(v.x, v.x, acc); acc = fmaf(v.y, v.y, acc);
        acc = fmaf(v.z, v.z, acc); acc = fmaf(v.w, v.w, acc);
    }
    cn[g] = acc;
}

#define BAR_N4 do { \
    __builtin_amdgcn_sched_barrier(0); \
    asm volatile("s_waitcnt vmcnt(4) lgkmcnt(0)" ::: "memory"); \
    __builtin_amdgcn_s_barrier(); \
    asm volatile("" ::: "memory"); \
    __builtin_amdgcn_sched_barrier(0); \
} while (0)

#define BAR_N0 do { \
    __builtin_amdgcn_sched_barrier(0); \
    asm volatile("s_waitcnt vmcnt(0) lgkmcnt(0)" ::: "memory"); \
    __builtin_amdgcn_s_barrier(); \
    asm volatile("" ::: "memory"); \
    __builtin_amdgcn_sched_barrier(0); \
} while (0)

__global__ __launch_bounds__(256, 3)
void rvq_main(const float* __restrict__ ze, const float* __restrict__ cbf,
              const _Float16* __restrict__ cbq, const float* __restrict__ cn,
              float* __restrict__ out)
{
    __shared__ __align__(16) char BB[3][CHUNK_BYTES];
    __shared__ int BIs[4][32];

    const int tid  = threadIdx.x;
    const int wid  = tid >> 6;
    const int lane = tid & 63;
    const int col  = lane & 31;
    const int h    = lane >> 5;
    const int rowbase = blockIdx.x * 128 + wid * 32;
    const int myrow   = rowbase + col;

    const float* zrow = ze + (size_t)myrow * DIM + 8 * h;
    int hist0 = 0, hist1 = 0, hist2 = 0, hist3 = 0;

#pragma unroll
    for (int s = 0; s < NCB; ++s) {
        // ---- recompute residual (streaming per c, exact order), quantize, xn ----
        v8h A0[8], A1[8];
        float pc[8];
#pragma unroll
        for (int c = 0; c < 8; ++c) {
            float r8[8];
            {
                const float4 v0 = *reinterpret_cast<const float4*>(zrow + 16 * c);
                const float4 v1 = *reinterpret_cast<const float4*>(zrow + 16 * c + 4);
                r8[0] = v0.x; r8[1] = v0.y; r8[2] = v0.z; r8[3] = v0.w;
                r8[4] = v1.x; r8[5] = v1.y; r8[6] = v1.z; r8[7] = v1.w;
            }
#pragma unroll
            for (int t = 0; t < s; ++t) {
                const int ht = (t == 0) ? hist0 : (t == 1) ? hist1 : (t == 2) ? hist2 : hist3;
                const float* qrow = cbf + ((size_t)(t * CBS) + ht) * DIM + 16 * c + 8 * h;
                const float4 q0 = *reinterpret_cast<const float4*>(qrow);
                const float4 q1 = *reinterpret_cast<const float4*>(qrow + 4);
                r8[0] -= q0.x; r8[1] -= q0.y; r8[2] -= q0.z; r8[3] -= q0.w;
                r8[4] -= q1.x; r8[5] -= q1.y; r8[6] -= q1.z; r8[7] -= q1.w;
            }
            float p[8];
#pragma unroll
            for (int j = 0; j < 8; ++j) {
                const float v = r8[j];
                p[j] = v * v;
                const _Float16 h0 = (_Float16)v;
                const float t = v - (float)h0;    // exact
                A0[c][j] = h0;
                A1[c][j] = (_Float16)(t * 4096.0f);
            }
            pc[c] = ((p[0] + p[1]) + (p[2] + p[3])) + ((p[4] + p[5]) + (p[6] + p[7]));
        }
        const float xnp = ((pc[0] + pc[1]) + (pc[2] + pc[3])) + ((pc[4] + pc[5]) + (pc[6] + pc[7]));
        const float xn_own = xnp + __shfl_xor(xnp, 32);
        float xns[16];
#pragma unroll
        for (int r = 0; r < 16; ++r)
            xns[r] = __shfl(xn_own, (r & 3) + 8 * (r >> 2) + 4 * h);

        const char* cbq_s = (const char*)cbq + (size_t)(s * 64) * CHUNK_BYTES;

        // ---- stage chunks 0,1 into BB[0], BB[1] ----
#pragma unroll
        for (int qq = 0; qq < 2; ++qq) {
            const char* gsrc = cbq_s + (size_t)qq * CHUNK_BYTES;
#pragma unroll
            for (int i = 0; i < 4; ++i) {
                const int blk = i * 4 + wid;
                __builtin_amdgcn_global_load_lds(
                    (const __attribute__((address_space(1))) void*)(gsrc + blk * 1024 + lane * 16),
                    (__attribute__((address_space(3))) void*)(&BB[qq][blk * 1024]), 16, 0, 0);
            }
        }
        BAR_N4;  // chunk0 landed everywhere (chunk1's 4 loads may remain in flight)

        float bestd[16];
        unsigned bq[4] = {0u, 0u, 0u, 0u};
#pragma unroll
        for (int r = 0; r < 16; ++r) bestd[r] = INFINITY;

        int cur = 0;
#pragma unroll 1
        for (int q = 0; q < 64; ++q) {
            const float cnv = cn[s * CBS + q * 32 + col];   // issued before prefetch (older in vmcnt)
            if (q < 62) {
                int pre = cur - 1; if (pre < 0) pre = 2;     // (cur+2)%3
                const char* gsrc = cbq_s + (size_t)(q + 2) * CHUNK_BYTES;
#pragma unroll
                for (int i = 0; i < 4; ++i) {
                    const int blk = i * 4 + wid;
                    __builtin_amdgcn_global_load_lds(
                        (const __attribute__((address_space(1))) void*)(gsrc + blk * 1024 + lane * 16),
                        (__attribute__((address_space(3))) void*)(&BB[pre][blk * 1024]), 16, 0, 0);
                }
            }
            const char* bb = &BB[cur][0];
            v16f aM, aC;
            {
                const v8h b0 = *reinterpret_cast<const v8h*>(bb + lane * 16);
                const v8h b1 = *reinterpret_cast<const v8h*>(bb + 8 * 1024 + lane * 16);
                const v16f Z = {0.f,0.f,0.f,0.f,0.f,0.f,0.f,0.f,0.f,0.f,0.f,0.f,0.f,0.f,0.f,0.f};
                aM = MFMA16(A0[0], b0, Z);
                aC = MFMA16(A1[0], b0, Z);
                aC = MFMA16(A0[0], b1, aC);
            }
#pragma unroll
            for (int c = 1; c < 8; ++c) {
                const v8h b0 = *reinterpret_cast<const v8h*>(bb + (size_t)c * 1024 + lane * 16);
                const v8h b1 = *reinterpret_cast<const v8h*>(bb + (size_t)(8 + c) * 1024 + lane * 16);
                aM = MFMA16(A0[c], b0, aM);
                aC = MFMA16(A1[c], b0, aC);
                aC = MFMA16(A0[c], b1, aC);
            }
#pragma unroll
            for (int r = 0; r < 16; ++r) {
                const float dotf = fmaf(aC[r], INV4096, aM[r]);
                const float d = fmaf(-2.0f, dotf, xns[r]) + cnv;  // matches ref rounding
                const bool take = d < bestd[r];
                bestd[r] = take ? d : bestd[r];
                const int w = r >> 2, sh = (r & 3) * 8;
                const unsigned nb = (bq[w] & ~(255u << sh)) | ((unsigned)q << sh);
                bq[w] = take ? nb : bq[w];
            }
            if (q < 62) { BAR_N4; } else { BAR_N0; }
            cur = (cur == 2) ? 0 : cur + 1;
        }

        // ---- unpack indices; argmin across 32 cols; ties -> lower idx ----
        int besti[16];
#pragma unroll
        for (int r = 0; r < 16; ++r)
            besti[r] = (int)((bq[r >> 2] >> ((r & 3) * 8)) & 255u) * 32 + col;
#pragma unroll
        for (int r = 0; r < 16; ++r) {
            float d = bestd[r]; int bi = besti[r];
#pragma unroll
            for (int m = 1; m <= 16; m <<= 1) {
                const float od = __shfl_xor(d, m);
                const int   oi = __shfl_xor(bi, m);
                const bool take = (od < d) || ((od == d) && (oi < bi));
                d  = take ? od : d;
                bi = take ? oi : bi;
            }
            bestd[r] = d; besti[r] = bi;
        }

        if (col == 0) {
#pragma unroll
            for (int r = 0; r < 16; ++r) {
                const int row16 = (r & 3) + 8 * (r >> 2) + 4 * h;
                BIs[wid][row16] = besti[r];
                out[ZQ_SIZE + (size_t)(rowbase + row16) * NCB + s] = (float)besti[r];
            }
        }
        asm volatile("s_waitcnt lgkmcnt(0)" ::: "memory");   // wave-local ds_write -> ds_read
        const int mybest = BIs[wid][col];
        if (s == 0) hist0 = mybest;
        else if (s == 1) hist1 = mybest;
        else if (s == 2) hist2 = mybest;
        else hist3 = mybest;
    }

    // ---- epilogue: recompute final residual; z_q = z_e - r; loss ----
    float lsum = 0.0f;
#pragma unroll
    for (int c = 0; c < 8; ++c) {
        float z8[8], r8[8];
        {
            const float4 v0 = *reinterpret_cast<const float4*>(zrow + 16 * c);
            const float4 v1 = *reinterpret_cast<const float4*>(zrow + 16 * c + 4);
            z8[0] = v0.x; z8[1] = v0.y; z8[2] = v0.z; z8[3] = v0.w;
            z8[4] = v1.x; z8[5] = v1.y; z8[6] = v1.z; z8[7] = v1.w;
        }
#pragma unroll
        for (int j = 0; j < 8; ++j) r8[j] = z8[j];
#pragma unroll
        for (int t = 0; t < 4; ++t) {
            const int ht = (t == 0) ? hist0 : (t == 1) ? hist1 : (t == 2) ? hist2 : hist3;
            const float* qrow = cbf + ((size_t)(t * CBS) + ht) * DIM + 16 * c + 8 * h;
            const float4 q0 = *reinterpret_cast<const float4*>(qrow);
            const float4 q1 = *reinterpret_cast<const float4*>(qrow + 4);
            r8[0] -= q0.x; r8[1] -= q0.y; r8[2] -= q0.z; r8[3] -= q0.w;
            r8[4] -= q1.x; r8[5] -= q1.y; r8[6] -= q1.z; r8[7] -= q1.w;
        }
        float4 o0, o1;
        o0.x = z8[0] - r8[0]; o0.y = z8[1] - r8[1]; o0.z = z8[2] - r8[2]; o0.w = z8[3] - r8[3];
        o1.x = z8[4] - r8[4]; o1.y = z8[5] - r8[5]; o1.z = z8[6] - r8[6]; o1.w = z8[7] - r8[7];
        float* orow = out + (size_t)myrow * DIM + 16 * c + 8 * h;
        *reinterpret_cast<float4*>(orow) = o0;
        *reinterpret_cast<float4*>(orow + 4) = o1;
#pragma unroll
        for (int j = 0; j < 8; ++j) lsum = fmaf(r8[j], r8[j], lsum);
    }
#pragma unroll
    for (int m = 1; m < 64; m <<= 1) lsum += __shfl_xor(lsum, m);
    if (lane == 0)
        atomicAdd(out + ZQ_SIZE + CODES_SIZE, lsum * (1.25f / 16777216.0f));
}

extern "C" void kernel_launch(void* const* d_in, const int* in_sizes, int n_in,
                              void* d_out, int out_size, void* d_ws, size_t ws_size,
                              hipStream_t stream)
{
    const float* ze  = (const float*)d_in[0];
    const float* cbf = (const float*)d_in[1];
    float* out = (float*)d_out;

    _Float16* cbq = (_Float16*)d_ws;
    float* cnall = (float*)((char*)d_ws + CBQ_TOTAL);

    hipMemsetAsync(out + ZQ_SIZE + CODES_SIZE, 0, sizeof(float), stream);

    prep_cb<<<256, 256, 0, stream>>>(cbf, cbq);
    prep_cn<<<32, 256, 0, stream>>>(cbf, cnall);
    rvq_main<<<NROWS / 128, 256, 0, stream>>>(ze, cbf, cbq, cnall, out);
}

// Round 6
// 960.880 us; speedup vs baseline: 1.0479x; 1.0479x over previous
//
#include <hip/hip_runtime.h>

typedef float v16f __attribute__((ext_vector_type(16)));
typedef _Float16 v8h __attribute__((ext_vector_type(8)));

#define NROWS 131072
#define DIM 128
#define NCB 4
#define CBS 2048
#define ZQ_SIZE ((size_t)NROWS * DIM)
#define CODES_SIZE ((size_t)NROWS * NCB)
#define CHUNK_BYTES 16384
#define CBQ_TOTAL ((size_t)NCB * 64 * CHUNK_BYTES)  /* 4 MiB */
#define INV4096 2.44140625e-4f

#define MFMA16(a, b, c) __builtin_amdgcn_mfma_f32_32x32x16_f16((a), (b), (c), 0, 0, 0)

// Tile codebook into per-chunk f16 2-limb image (identical to round 3).
__global__ void prep_cb(const float* __restrict__ cb, _Float16* __restrict__ cbq) {
    const int g = blockIdx.x * 256 + threadIdx.x;   // 65536 threads
    const int c   = g & 7;
    const int col = (g >> 3) & 31;
    const int q   = (g >> 8) & 63;
    const int s   = g >> 14;
    const float* src = cb + (size_t)(s * CBS + q * 32 + col) * DIM + 16 * c;
    _Float16* base = cbq + (size_t)(s * 64 + q) * 8192;  // f16 elems
#pragma unroll
    for (int hh = 0; hh < 2; ++hh) {
        v8h p0, p1;
#pragma unroll
        for (int j = 0; j < 8; ++j) {
            const float v = src[8 * hh + j];
            const _Float16 h0 = (_Float16)v;
            const float t = v - (float)h0;        // exact
            p0[j] = h0;
            p1[j] = (_Float16)(t * 4096.0f);      // scaled limb: normal range
        }
        *reinterpret_cast<v8h*>(base + (size_t)c * 512 + (hh * 32 + col) * 8) = p0;
        *reinterpret_cast<v8h*>(base + (size_t)(8 + c) * 512 + (hh * 32 + col) * 8) = p1;
    }
}

__global__ void prep_cn(const float* __restrict__ cb, float* __restrict__ cn) {
    const int g = blockIdx.x * 256 + threadIdx.x;   // 8192 threads
    const float* src = cb + (size_t)g * DIM;
    float acc = 0.0f;
    for (int i = 0; i < 32; ++i) {
        const float4 v = *reinterpret_cast<const float4*>(src + 4 * i);
        acc = fmaf(v.x, v.x, acc); acc = fmaf(v.y, v.y, acc);
        acc = fmaf(v.z, v.z, acc); acc = fmaf(v.w, v.w, acc);
    }
    cn[g] = acc;
}

// Exact 3-limb split of f32: v == h0 + h1*2^-12 + h2*2^-24 (bit-exact; each
// subtraction is same-binade exact, h2 holds the <=3 remaining mantissa bits).
__device__ __forceinline__ void split3(float v, _Float16* h0, _Float16* h1, _Float16* h2) {
    const _Float16 a = (_Float16)v;
    const float t1 = v - (float)a;           // exact
    const float s1 = t1 * 4096.0f;           // exact (pow2)
    const _Float16 b = (_Float16)s1;
    const float s2 = (s1 - (float)b) * 4096.0f;  // exact
    *h0 = a; *h1 = b; *h2 = (_Float16)s2;    // last cast exact (<=3 bits left)
}

__global__ __launch_bounds__(256, 3)
void rvq_main(const float* __restrict__ ze, const float* __restrict__ cbf,
              const _Float16* __restrict__ cbq, const float* __restrict__ cn,
              float* __restrict__ out)
{
    __shared__ __align__(16) char BB[2][CHUNK_BYTES];
    __shared__ int BIs[4][32];

    const int tid  = threadIdx.x;
    const int wid  = tid >> 6;
    const int lane = tid & 63;
    const int col  = lane & 31;
    const int h    = lane >> 5;
    const int rowbase = blockIdx.x * 128 + wid * 32;
    const int myrow   = rowbase + col;

    const float* zrow = ze + (size_t)myrow * DIM + 8 * h;
    // A2 limb scratch: block-private region of the (not-yet-written) z_q output
    _Float16* a2 = (_Float16*)out + (size_t)blockIdx.x * 32768;  // slot (c*256+tid)*8

    v8h A0[8], A1[8];
    int mylast = 0;

    for (int s = 0; s < NCB; ++s) {
        // ---- build stage-s residual limbs (exact f32 chain) + x_norm ----
        float pc[8];
        if (s == 0) {
#pragma unroll
            for (int c = 0; c < 8; ++c) {
                const float4 v0 = *reinterpret_cast<const float4*>(zrow + 16 * c);
                const float4 v1 = *reinterpret_cast<const float4*>(zrow + 16 * c + 4);
                float v[8] = {v0.x, v0.y, v0.z, v0.w, v1.x, v1.y, v1.z, v1.w};
                v8h a2v;
                float p[8];
#pragma unroll
                for (int j = 0; j < 8; ++j) {
                    p[j] = v[j] * v[j];
                    _Float16 x0, x1, x2;
                    split3(v[j], &x0, &x1, &x2);
                    A0[c][j] = x0; A1[c][j] = x1; a2v[j] = x2;
                }
                *reinterpret_cast<v8h*>(a2 + ((size_t)c * 256 + tid) * 8) = a2v;
                pc[c] = ((p[0] + p[1]) + (p[2] + p[3])) + ((p[4] + p[5]) + (p[6] + p[7]));
            }
        } else {
            const float* qrow = cbf + ((size_t)((s - 1) * CBS) + mylast) * DIM + 8 * h;
#pragma unroll
            for (int c = 0; c < 8; ++c) {
                const v8h a2v_old = *reinterpret_cast<const v8h*>(a2 + ((size_t)c * 256 + tid) * 8);
                const float4 q0 = *reinterpret_cast<const float4*>(qrow + 16 * c);
                const float4 q1 = *reinterpret_cast<const float4*>(qrow + 16 * c + 4);
                const float qv[8] = {q0.x, q0.y, q0.z, q0.w, q1.x, q1.y, q1.z, q1.w};
                v8h a2v;
                float p[8];
#pragma unroll
                for (int j = 0; j < 8; ++j) {
                    // exact reconstruction of previous residual, then ref-identical update
                    const float vr = fmaf((float)a2v_old[j], 0x1p-24f,
                                     fmaf((float)A1[c][j], 0x1p-12f, (float)A0[c][j]));
                    const float v = vr - qv[j];
                    p[j] = v * v;
                    _Float16 x0, x1, x2;
                    split3(v, &x0, &x1, &x2);
                    A0[c][j] = x0; A1[c][j] = x1; a2v[j] = x2;
                }
                *reinterpret_cast<v8h*>(a2 + ((size_t)c * 256 + tid) * 8) = a2v;
                pc[c] = ((p[0] + p[1]) + (p[2] + p[3])) + ((p[4] + p[5]) + (p[6] + p[7]));
            }
        }
        const float xnp = ((pc[0] + pc[1]) + (pc[2] + pc[3])) + ((pc[4] + pc[5]) + (pc[6] + pc[7]));
        const float xn_own = xnp + __shfl_xor(xnp, 32);
        float xns[16];
#pragma unroll
        for (int r = 0; r < 16; ++r)
            xns[r] = __shfl(xn_own, (r & 3) + 8 * (r >> 2) + 4 * h);

        const char* cbq_s = (const char*)cbq + (size_t)(s * 64) * CHUNK_BYTES;

        // ---- stage chunk 0 ----
#pragma unroll
        for (int i = 0; i < 4; ++i) {
            const int blk = i * 4 + wid;
            __builtin_amdgcn_global_load_lds(
                (const __attribute__((address_space(1))) void*)(cbq_s + blk * 1024 + lane * 16),
                (__attribute__((address_space(3))) void*)(&BB[0][blk * 1024]), 16, 0, 0);
        }
        __syncthreads();

        float bestd[16]; int besti[16];
#pragma unroll
        for (int r = 0; r < 16; ++r) { bestd[r] = INFINITY; besti[r] = 0; }

#pragma unroll 1
        for (int q = 0; q < 64; ++q) {
            const int cur = q & 1;
            const float cnv = cn[s * CBS + q * 32 + col];
            if (q < 63) {  // prefetch next chunk into other buffer
                const char* gq = cbq_s + (size_t)(q + 1) * CHUNK_BYTES;
#pragma unroll
                for (int i = 0; i < 4; ++i) {
                    const int blk = i * 4 + wid;
                    __builtin_amdgcn_global_load_lds(
                        (const __attribute__((address_space(1))) void*)(gq + blk * 1024 + lane * 16),
                        (__attribute__((address_space(3))) void*)(&BB[cur ^ 1][blk * 1024]), 16, 0, 0);
                }
            }
            const char* bb = &BB[cur][0];
            v16f aM, aC;
            __builtin_amdgcn_s_setprio(1);
            {
                const v8h b0 = *reinterpret_cast<const v8h*>(bb + lane * 16);
                const v8h b1 = *reinterpret_cast<const v8h*>(bb + 8 * 1024 + lane * 16);
                const v16f Z = {0.f,0.f,0.f,0.f,0.f,0.f,0.f,0.f,0.f,0.f,0.f,0.f,0.f,0.f,0.f,0.f};
                aM = MFMA16(A0[0], b0, Z);
                aC = MFMA16(A1[0], b0, Z);
                aC = MFMA16(A0[0], b1, aC);
            }
#pragma unroll
            for (int c = 1; c < 8; ++c) {
                const v8h b0 = *reinterpret_cast<const v8h*>(bb + (size_t)c * 1024 + lane * 16);
                const v8h b1 = *reinterpret_cast<const v8h*>(bb + (size_t)(8 + c) * 1024 + lane * 16);
                aM = MFMA16(A0[c], b0, aM);
                aC = MFMA16(A1[c], b0, aC);
                aC = MFMA16(A0[c], b1, aC);
            }
            __builtin_amdgcn_s_setprio(0);
            const int code = (q << 5) | col;
#pragma unroll
            for (int r = 0; r < 16; ++r) {
                const float dotf = fmaf(aC[r], INV4096, aM[r]);
                const float d = fmaf(-2.0f, dotf, xns[r]) + cnv;  // matches ref rounding
                const bool take = d < bestd[r];
                bestd[r] = take ? d : bestd[r];
                besti[r] = take ? code : besti[r];
            }
            __syncthreads();
        }

        // ---- argmin across 32 cols (within each half-wave); ties -> lower idx ----
#pragma unroll
        for (int r = 0; r < 16; ++r) {
            float d = bestd[r]; int bi = besti[r];
#pragma unroll
            for (int m = 1; m <= 16; m <<= 1) {
                const float od = __shfl_xor(d, m);
                const int   oi = __shfl_xor(bi, m);
                const bool take = (od < d) || ((od == d) && (oi < bi));
                d  = take ? od : d;
                bi = take ? oi : bi;
            }
            bestd[r] = d; besti[r] = bi;
        }

        if (col == 0) {
#pragma unroll
            for (int r = 0; r < 16; ++r) {
                const int row16 = (r & 3) + 8 * (r >> 2) + 4 * h;
                BIs[wid][row16] = besti[r];
                out[ZQ_SIZE + (size_t)(rowbase + row16) * NCB + s] = (float)besti[r];
            }
        }
        __syncthreads();
        mylast = BIs[wid][col];
    }

    // ---- final pass: reconstruct, subtract stage-3 code, z_q & loss ----
    v8h a2r[8];
#pragma unroll
    for (int c = 0; c < 8; ++c)
        a2r[c] = *reinterpret_cast<const v8h*>(a2 + ((size_t)c * 256 + tid) * 8);
    __syncthreads();   // all a2 reads landed before anyone overwrites the slab with z_q

    const float* qrow = cbf + ((size_t)(3 * CBS) + mylast) * DIM + 8 * h;
    float lsum = 0.0f;
#pragma unroll
    for (int c = 0; c < 8; ++c) {
        const float4 q0 = *reinterpret_cast<const float4*>(qrow + 16 * c);
        const float4 q1 = *reinterpret_cast<const float4*>(qrow + 16 * c + 4);
        const float4 z0 = *reinterpret_cast<const float4*>(zrow + 16 * c);
        const float4 z1 = *reinterpret_cast<const float4*>(zrow + 16 * c + 4);
        const float qv[8] = {q0.x, q0.y, q0.z, q0.w, q1.x, q1.y, q1.z, q1.w};
        const float zv[8] = {z0.x, z0.y, z0.z, z0.w, z1.x, z1.y, z1.z, z1.w};
        float o[8];
#pragma unroll
        for (int j = 0; j < 8; ++j) {
            const float vr = fmaf((float)a2r[c][j], 0x1p-24f,
                             fmaf((float)A1[c][j], 0x1p-12f, (float)A0[c][j]));
            const float v = vr - qv[j];          // final residual (ref-identical)
            o[j] = zv[j] - v;                    // z_q
            lsum = fmaf(v, v, lsum);
        }
        float4 o0 = {o[0], o[1], o[2], o[3]};
        float4 o1 = {o[4], o[5], o[6], o[7]};
        float* orow = out + (size_t)myrow * DIM + 16 * c + 8 * h;
        *reinterpret_cast<float4*>(orow) = o0;
        *reinterpret_cast<float4*>(orow + 4) = o1;
    }
#pragma unroll
    for (int m = 1; m < 64; m <<= 1) lsum += __shfl_xor(lsum, m);
    if (lane == 0)
        atomicAdd(out + ZQ_SIZE + CODES_SIZE, lsum * (1.25f / 16777216.0f));
}

extern "C" void kernel_launch(void* const* d_in, const int* in_sizes, int n_in,
                              void* d_out, int out_size, void* d_ws, size_t ws_size,
                              hipStream_t stream)
{
    const float* ze  = (const float*)d_in[0];
    const float* cbf = (const float*)d_in[1];
    float* out = (float*)d_out;

    _Float16* cbq = (_Float16*)d_ws;
    float* cnall = (float*)((char*)d_ws + CBQ_TOTAL);

    (void)hipMemsetAsync(out + ZQ_SIZE + CODES_SIZE, 0, sizeof(float), stream);

    prep_cb<<<256, 256, 0, stream>>>(cbf, cbq);
    prep_cn<<<32, 256, 0, stream>>>(cbf, cnall);
    rvq_main<<<NROWS / 128, 256, 0, stream>>>(ze, cbf, cbq, cnall, out);
}